// Round 4
// baseline (198.840 us; speedup 1.0000x reference)
//
#include <hip/hip_runtime.h>
#include <math.h>

typedef short s16x8 __attribute__((ext_vector_type(8)));
typedef float f32x4 __attribute__((ext_vector_type(4)));
typedef float f32x16 __attribute__((ext_vector_type(16)));
typedef unsigned short u16;

#define B_ 2
#define T_ 2048
#define HN_ 16

// ---------------- helpers ----------------
__device__ __forceinline__ u16 f2bf(float f) {
  union { float f; unsigned u; } v; v.f = f;
  unsigned r = v.u + 0x7FFFu + ((v.u >> 16) & 1u);   // RNE (finite inputs)
  return (u16)(r >> 16);
}
__device__ __forceinline__ float bf2f(u16 b) {
  union { unsigned u; float f; } v; v.u = ((unsigned)b) << 16;
  return v.f;
}
__device__ __forceinline__ float softplus_f(float v) {
  return fmaxf(v, 0.f) + log1pf(__expf(-fabsf(v)));
}
__device__ __forceinline__ f32x4 mfma16(s16x8 a, s16x8 b, f32x4 c) {
  return __builtin_amdgcn_mfma_f32_16x16x32_bf16(a, b, c, 0, 0, 0);
}
__device__ __forceinline__ f32x16 mfma32(s16x8 a, s16x8 b, f32x16 c) {
  return __builtin_amdgcn_mfma_f32_32x32x16_bf16(a, b, c, 0, 0, 0);
}
__device__ __forceinline__ void gload16(void* lds, const void* g) {
  __builtin_amdgcn_global_load_lds(
      (const __attribute__((address_space(1))) unsigned int*)g,
      (__attribute__((address_space(3))) unsigned int*)lds, 16, 0, 0);
}
__device__ __forceinline__ unsigned cvtpk(float lo, float hi) {
  unsigned r;
  asm("v_cvt_pk_bf16_f32 %0, %1, %2" : "=v"(r) : "v"(lo), "v"(hi));
  return r;
}

// ---------------- f32 -> bf16 convert with GEMM-tile swizzle ----------------
__global__ __launch_bounds__(256) void conv_swz(
    const float* __restrict__ in, u16* __restrict__ out, int nchunks)
{
  int c = blockIdx.x * 256 + threadIdx.x;
  if (c >= nchunks) return;
  int row = c >> 7, cc = c & 127;           // 128 chunks per 1024-elem row
  int ks = cc >> 3, ch = cc & 7;
  const float4* src = (const float4*)(in + ((size_t)row << 10) + (cc << 3));
  float4 a = src[0], b = src[1];
  s16x8 o;
  o[0] = (short)f2bf(a.x); o[1] = (short)f2bf(a.y);
  o[2] = (short)f2bf(a.z); o[3] = (short)f2bf(a.w);
  o[4] = (short)f2bf(b.x); o[5] = (short)f2bf(b.y);
  o[6] = (short)f2bf(b.z); o[7] = (short)f2bf(b.w);
  *(s16x8*)(out + ((size_t)row << 10) + (ks << 6) + ((ch ^ (row & 7)) << 3)) = o;
}

// ---------------- trig tables (f32) ----------------
__global__ __launch_bounds__(256) void build_tables(
    float* __restrict__ postab, float* __restrict__ dtab,
    const float* __restrict__ delta)
{
  int idx = blockIdx.x * 256 + threadIdx.x;   // < T_*64
  int t = idx >> 6, d = idx & 63;
  float invf = powf(10000.f, -(float)d * (1.0f / 64.0f));
  float ang = (float)t * invf;
  float sp, cp;
  sincosf(ang, &sp, &cp);
  postab[idx * 2 + 0] = cp;
  postab[idx * 2 + 1] = sp;
  if (idx < HN_ * 64) {
    float dl = delta[idx];
    dl = fminf(fmaxf(dl, -6.2831853071795865f), 0.f);
    float sd, cd;
    sincosf(dl, &sd, &cd);
    dtab[idx * 2 + 0] = cd;
    dtab[idx * 2 + 1] = sd;
  }
}

// ---------------- bf16 MFMA GEMM (NT): C = A * B^T ----------------
template<int OUTK>
__global__ __launch_bounds__(256) void gemm_nt_mfma(
    const u16* __restrict__ A, const u16* __restrict__ Bw,
    void* __restrict__ Cout, int N)
{
  __shared__ u16 As[128 * 64];
  __shared__ u16 Bs[128 * 64];
  const int tid = threadIdx.x;
  const int w = tid >> 6, l = tid & 63, g = l >> 4;
  const int bm = blockIdx.y * 128, bn = blockIdx.x * 128;
  const int wr = w >> 1, wc = w & 1;
  const int K = 1024;

  const f32x4 zero = {0.f, 0.f, 0.f, 0.f};
  f32x4 acc[4][4];
  #pragma unroll
  for (int mt = 0; mt < 4; ++mt)
    #pragma unroll
    for (int nt = 0; nt < 4; ++nt) acc[mt][nt] = zero;

  for (int kt = 0; kt < K; kt += 64) {
    __syncthreads();
    #pragma unroll
    for (int j = 0; j < 4; ++j) {
      int cid = (j * 4 + w) * 64 + l;           // chunk 0..1023
      int row = cid >> 3, cc = cid & 7;
      gload16(As + ((j * 4 + w) << 9), A  + (size_t)(bm + row) * K + kt + cc * 8);
      gload16(Bs + ((j * 4 + w) << 9), Bw + (size_t)(bn + row) * K + kt + cc * 8);
    }
    __syncthreads();
    #pragma unroll
    for (int ks = 0; ks < 2; ++ks) {
      s16x8 af[4], bfr[4];
      #pragma unroll
      for (int mt = 0; mt < 4; ++mt) {
        int rr = wr * 64 + mt * 16 + (l & 15);
        af[mt] = *(const s16x8*)(As + rr * 64 + (((ks * 4 + g) ^ (rr & 7)) << 3));
      }
      #pragma unroll
      for (int nt = 0; nt < 4; ++nt) {
        int rr = wc * 64 + nt * 16 + (l & 15);
        bfr[nt] = *(const s16x8*)(Bs + rr * 64 + (((ks * 4 + g) ^ (rr & 7)) << 3));
      }
      #pragma unroll
      for (int mt = 0; mt < 4; ++mt)
        #pragma unroll
        for (int nt = 0; nt < 4; ++nt)
          acc[mt][nt] = mfma16(af[mt], bfr[nt], acc[mt][nt]);
    }
  }

  #pragma unroll
  for (int mt = 0; mt < 4; ++mt)
    #pragma unroll
    for (int nt = 0; nt < 4; ++nt)
      #pragma unroll
      for (int r = 0; r < 4; ++r) {
        int row = bm + wr * 64 + mt * 16 + g * 4 + r;
        int col = bn + wc * 64 + nt * 16 + (l & 15);
        if (OUTK == 0)
          ((u16*)Cout)[(size_t)row * N + col] = f2bf(acc[mt][nt][r]);
        else
          ((float*)Cout)[(size_t)row * N + col] = acc[mt][nt][r];
      }
}

// ---------------- PoPE prepass (Kp swizzled, Vt swizzled) ----------------
__global__ __launch_bounds__(256) void pope_prep(
    const u16* __restrict__ qkvb, const float* __restrict__ postab,
    const float* __restrict__ dtab, u16* __restrict__ Kp, u16* __restrict__ Vtp)
{
  __shared__ u16 Vs[64][72];
  const int tb = blockIdx.x, h = blockIdx.y, b = blockIdx.z;
  const int t0 = tb * 64, tid = threadIdx.x;
  const int tl = tid >> 2, j = tid & 3, d0 = j * 16;
  const int t = t0 + tl;
  const size_t bh = (size_t)b * HN_ + h;
  const size_t qrow = (size_t)(b * T_ + t) * 3072 + h * 64;

  {
    s16x8 k0 = *(const s16x8*)(qkvb + qrow + 1024 + d0);
    s16x8 k1 = *(const s16x8*)(qkvb + qrow + 1024 + d0 + 8);
    const float2* pt = (const float2*)postab + (size_t)t * 64 + d0;
    const float2* dt = (const float2*)dtab + h * 64 + d0;
    s16x8 r0, r1, i0, i1;
    #pragma unroll
    for (int i = 0; i < 8; ++i) {
      float mu = softplus_f(bf2f((u16)k0[i]));
      float2 cs = pt[i]; float2 dc = dt[i];
      r0[i] = (short)f2bf(mu * (cs.x * dc.x - cs.y * dc.y));
      i0[i] = (short)f2bf(mu * (cs.y * dc.x + cs.x * dc.y));
    }
    #pragma unroll
    for (int i = 0; i < 8; ++i) {
      float mu = softplus_f(bf2f((u16)k1[i]));
      float2 cs = pt[8 + i]; float2 dc = dt[8 + i];
      r1[i] = (short)f2bf(mu * (cs.x * dc.x - cs.y * dc.y));
      i1[i] = (short)f2bf(mu * (cs.y * dc.x + cs.x * dc.y));
    }
    u16* Krow = Kp + (bh * T_ + t) * 128;
    int sw = t & 7;
    int c0 = d0 >> 3;
    *(s16x8*)(Krow + ((c0 ^ sw) << 3))       = r0;
    *(s16x8*)(Krow + (((c0 + 1) ^ sw) << 3)) = r1;
    *(s16x8*)(Krow + (((c0 + 8) ^ sw) << 3)) = i0;
    *(s16x8*)(Krow + (((c0 + 9) ^ sw) << 3)) = i1;
  }

  {
    s16x8 v0 = *(const s16x8*)(qkvb + qrow + 2048 + d0);
    s16x8 v1 = *(const s16x8*)(qkvb + qrow + 2048 + d0 + 8);
    *(s16x8*)(&Vs[tl][d0])     = v0;
    *(s16x8*)(&Vs[tl][d0 + 8]) = v1;
  }
  __syncthreads();
  {
    const int d = tid >> 2, jj = tid & 3, ts0 = jj * 16;
    u16* Vrow = Vtp + (bh * 64 + d) * T_;
    int swd = d & 7;
    s16x8 o0, o1;
    #pragma unroll
    for (int i = 0; i < 8; ++i) {
      o0[i] = (short)Vs[ts0 + i][d];
      o1[i] = (short)Vs[ts0 + 8 + i][d];
    }
    int cc0 = ts0 >> 3;
    *(s16x8*)(Vrow + t0 + ((cc0 ^ swd) << 3))       = o0;
    *(s16x8*)(Vrow + t0 + (((cc0 + 1) ^ swd) << 3)) = o1;
  }
}

// ---------------- MFMA flash attention, 32x32, double-buffered ----------------
// 4 waves x 32 q-rows = 128 q-rows/block. KV tile = 64. 2-phase pipeline:
// issue tile t+1's global_load_lds, counted vmcnt(6) keeps them in flight
// across raw s_barrier (no __syncthreads vmcnt(0) drain).
__global__ __launch_bounds__(256) void attn_mfma32(
    const u16* __restrict__ qkvb, const u16* __restrict__ Kp,
    const u16* __restrict__ Vtp, const float* __restrict__ postab,
    u16* __restrict__ yb)
{
  __shared__ u16 smem[2][12288];             // 2 x (K 16KB + Vt 8KB) = 48 KB
  const int h = blockIdx.y, b = blockIdx.z;
  const int qt = (int)gridDim.x - 1 - (int)blockIdx.x;   // heavy blocks first
  const int Qb = qt * 128;
  const int tid = threadIdx.x, w = tid >> 6, l = tid & 63;
  const int hi = l >> 5, ln = l & 31;
  const size_t bh = (size_t)b * HN_ + h;

  const float LS = 0.125f * 1.4426950408889634f;   // scale * log2(e)
  const float THRL = 11.5f;                        // defer-max threshold (log2)

  const u16* Kpb = Kp + bh * T_ * 128;
  const u16* Vtb = Vtp + bh * 64 * T_;

  // per-wave share of one tile's staging: 4 K-chunks + 2 V-chunks = 6 gloads
  auto STAGE = [&](int buf, int s0) {
    u16* Kd = smem[buf];
    u16* Vd = smem[buf] + 8192;
    #pragma unroll
    for (int j = 0; j < 4; ++j) {
      int cid = (j * 4 + w) * 64 + l;          // 0..1023
      int row = cid >> 4, cc = cid & 15;
      gload16(Kd + ((j * 4 + w) << 9), Kpb + (size_t)(s0 + row) * 128 + cc * 8);
    }
    #pragma unroll
    for (int j = 0; j < 2; ++j) {
      int cid = (j * 4 + w) * 64 + l;          // 0..511
      int row = cid >> 3, cc = cid & 7;
      gload16(Vd + ((j * 4 + w) << 9), Vtb + (size_t)row * T_ + s0 + cc * 8);
    }
  };

  // ---- Q fragments: 8 k-steps of 16 over cat-dim 128 (B-operand layout) ----
  const int q = Qb + w * 32 + ln;
  s16x8 qf[8];
  {
    const u16* qrp = qkvb + (size_t)(b * T_ + q) * 3072 + h * 64;
    const float2* pt = (const float2*)postab + (size_t)q * 64;
    #pragma unroll
    for (int kb = 0; kb < 4; ++kb) {
      int d0 = kb * 16 + hi * 8;
      s16x8 mu8 = *(const s16x8*)(qrp + d0);
      #pragma unroll
      for (int i = 0; i < 8; ++i) {
        float mu = softplus_f(bf2f((u16)mu8[i]));
        float2 cs = pt[d0 + i];
        qf[kb][i]     = (short)f2bf(mu * cs.x);
        qf[kb + 4][i] = (short)f2bf(mu * cs.y);
      }
    }
  }

  const f32x16 zero16 = {0.f,0.f,0.f,0.f,0.f,0.f,0.f,0.f,
                         0.f,0.f,0.f,0.f,0.f,0.f,0.f,0.f};
  f32x16 o0 = zero16, o1 = zero16;
  float m = -3e38f, lsum = 0.f;
  const int ntiles = 2 * qt + 2;

  STAGE(0, 0);                                   // prologue: tile 0 in flight

  for (int st = 0; st < ntiles; ++st) {
    const int cur = st & 1;
    const int s0 = st * 64;
    __builtin_amdgcn_s_barrier();                // A: prev compute done
    if (st + 1 < ntiles) {
      STAGE(cur ^ 1, s0 + 64);
      asm volatile("s_waitcnt vmcnt(6)" ::: "memory");  // tile-st loads done
    } else {
      asm volatile("s_waitcnt vmcnt(0)" ::: "memory");
    }
    __builtin_amdgcn_s_barrier();                // B: tile ready for all waves
    __builtin_amdgcn_sched_barrier(0);

    const u16* Ks  = smem[cur];
    const u16* Vts = smem[cur] + 8192;

    const bool active = s0 <= (Qb + w * 32 + 31);
    if (active) {
      const bool needmask = (s0 + 63) > (Qb + w * 32);

      // ---- QK^T (swapped): C[s][q] ----
      f32x16 sacc0 = zero16, sacc1 = zero16;
      __builtin_amdgcn_s_setprio(1);
      #pragma unroll
      for (int ks = 0; ks < 8; ++ks) {
        int r0_ = ln, r1_ = 32 + ln;
        s16x8 kf0 = *(const s16x8*)(Ks + r0_ * 128 + (((2 * ks + hi) ^ (r0_ & 7)) << 3));
        s16x8 kf1 = *(const s16x8*)(Ks + r1_ * 128 + (((2 * ks + hi) ^ (r1_ & 7)) << 3));
        sacc0 = mfma32(kf0, qf[ks], sacc0);
        sacc1 = mfma32(kf1, qf[ks], sacc1);
      }
      __builtin_amdgcn_s_setprio(0);

      // ---- masked scores ----
      float sc[2][16];
      #pragma unroll
      for (int j = 0; j < 16; ++j) { sc[0][j] = sacc0[j]; sc[1][j] = sacc1[j]; }
      if (needmask) {
        #pragma unroll
        for (int a = 0; a < 2; ++a)
          #pragma unroll
          for (int j = 0; j < 16; ++j) {
            int sg = s0 + a * 32 + (j & 3) + 8 * (j >> 2) + 4 * hi;
            if (sg > q) sc[a][j] = -3e38f;
          }
      }

      // ---- online softmax (log2 domain, defer-max) ----
      float pm = -3e38f;
      #pragma unroll
      for (int j = 0; j < 16; ++j) pm = fmaxf(pm, fmaxf(sc[0][j], sc[1][j]));
      pm = fmaxf(pm, __shfl_xor(pm, 32));
      float pmax = pm * LS;

      if (__any(pmax > m + THRL)) {
        float mnew = fmaxf(m, pmax);
        float corr = exp2f(m - mnew);
        m = mnew;
        lsum *= corr;
        #pragma unroll
        for (int j = 0; j < 16; ++j) {
          float cj = __shfl(corr, (j & 3) + 8 * (j >> 2) + 4 * hi);
          o0[j] *= cj; o1[j] *= cj;
        }
      }

      float pv[2][16];
      float rs = 0.f;
      #pragma unroll
      for (int a = 0; a < 2; ++a)
        #pragma unroll
        for (int j = 0; j < 16; ++j) {
          float p = exp2f(fmaf(sc[a][j], LS, -m));
          pv[a][j] = p; rs += p;
        }
      rs += __shfl_xor(rs, 32);
      lsum += rs;

      // ---- P -> bf16 A-frags (in-register redistribution) ----
      s16x8 pa[4];
      #pragma unroll
      for (int ks = 0; ks < 4; ++ks) {
        const int a = ks >> 1, bb = (ks & 1) * 8;
        unsigned pk01 = cvtpk(pv[a][bb + 0], pv[a][bb + 1]);
        unsigned pk23 = cvtpk(pv[a][bb + 2], pv[a][bb + 3]);
        unsigned pk45 = cvtpk(pv[a][bb + 4], pv[a][bb + 5]);
        unsigned pk67 = cvtpk(pv[a][bb + 6], pv[a][bb + 7]);
        unsigned sv0 = hi ? pk01 : pk45;
        unsigned sv1 = hi ? pk23 : pk67;
        unsigned r0 = (unsigned)__shfl_xor((int)sv0, 32);
        unsigned r1 = (unsigned)__shfl_xor((int)sv1, 32);
        union { unsigned u[4]; s16x8 v; } pu;
        pu.u[0] = hi ? r0 : pk01;
        pu.u[1] = hi ? r1 : pk23;
        pu.u[2] = hi ? pk45 : r0;
        pu.u[3] = hi ? pk67 : r1;
        pa[ks] = pu.v;
      }

      // ---- PV: o[q][d] += P x V ----
      __builtin_amdgcn_s_setprio(1);
      #pragma unroll
      for (int ks = 0; ks < 4; ++ks) {
        int rd0 = ln, rd1 = 32 + ln;
        s16x8 vb0 = *(const s16x8*)(Vts + rd0 * 64 + (((2 * ks + hi) ^ (rd0 & 7)) << 3));
        s16x8 vb1 = *(const s16x8*)(Vts + rd1 * 64 + (((2 * ks + hi) ^ (rd1 & 7)) << 3));
        o0 = mfma32(pa[ks], vb0, o0);
        o1 = mfma32(pa[ks], vb1, o1);
      }
      __builtin_amdgcn_s_setprio(0);
    }
  }

  // ---- epilogue: divide by l, store swizzled bf16 ----
  float linv = 1.0f / lsum;
  #pragma unroll
  for (int j = 0; j < 16; ++j) {
    float lj = __shfl(linv, (j & 3) + 8 * (j >> 2) + 4 * hi);
    int qrow = Qb + w * 32 + (j & 3) + 8 * (j >> 2) + 4 * hi;
    size_t rb = (size_t)(b * T_ + qrow) * 1024 + h * 64;
    #pragma unroll
    for (int nt = 0; nt < 2; ++nt) {
      int dcol = nt * 32 + ln;
      float val = (nt ? o1[j] : o0[j]) * lj;
      int ch = dcol >> 3;
      yb[rb + ((ch ^ (qrow & 7)) << 3) + (dcol & 7)] = f2bf(val);
    }
  }
}

// ---------------------------------------------------------------------------
extern "C" void kernel_launch(void* const* d_in, const int* in_sizes, int n_in,
                              void* d_out, int out_size, void* d_ws, size_t ws_size,
                              hipStream_t stream)
{
  const float* x      = (const float*)d_in[0];   // (B,T,C)
  const float* w_attn = (const float*)d_in[1];   // (3C,C)
  const float* w_proj = (const float*)d_in[2];   // (C,C)
  const float* delta  = (const float*)d_in[3];   // (H,D)
  float* out = (float*)d_out;

  char* p = (char*)d_ws;
  u16* xb     = (u16*)p;  p += (size_t)4096 * 1024 * 2;
  u16* wab    = (u16*)p;  p += (size_t)3072 * 1024 * 2;
  u16* wpb    = (u16*)p;  p += (size_t)1024 * 1024 * 2;
  u16* qkvb   = (u16*)p;  p += (size_t)4096 * 3072 * 2;
  u16* yb     = (u16*)p;  p += (size_t)4096 * 1024 * 2;
  u16* Kp     = (u16*)p;  p += (size_t)B_ * HN_ * T_ * 128 * 2;
  u16* Vtp    = (u16*)p;  p += (size_t)B_ * HN_ * 64 * T_ * 2;
  float* postab = (float*)p; p += (size_t)T_ * 64 * 2 * 4;
  float* dtab   = (float*)p; p += (size_t)HN_ * 64 * 2 * 4;

  conv_swz<<<(4096 * 128) / 256, 256, 0, stream>>>(x, xb, 4096 * 128);
  conv_swz<<<(3072 * 128) / 256, 256, 0, stream>>>(w_attn, wab, 3072 * 128);
  conv_swz<<<(1024 * 128) / 256, 256, 0, stream>>>(w_proj, wpb, 1024 * 128);
  build_tables<<<(T_ * 64) / 256, 256, 0, stream>>>(postab, dtab, delta);

  gemm_nt_mfma<0><<<dim3(3072 / 128, 4096 / 128), 256, 0, stream>>>(xb, wab, qkvb, 3072);
  pope_prep<<<dim3(T_ / 64, HN_, B_), 256, 0, stream>>>(qkvb, postab, dtab, Kp, Vtp);
  attn_mfma32<<<dim3(T_ / 128, HN_, B_), 256, 0, stream>>>(qkvb, Kp, Vtp, postab, yb);
  gemm_nt_mfma<1><<<dim3(1024 / 128, 4096 / 128), 256, 0, stream>>>(yb, wpb, out, 1024);
}